// Round 2
// baseline (952.106 us; speedup 1.0000x reference)
//
#include <hip/hip_runtime.h>
#include <hip/hip_bf16.h>

// DILATE loss, fused soft-DTW fwd+bwd, wave-skewed wavefront DP.
// Thread tid owns row i = tid. Lane l of wave w computes cell (i, j) at
// local step t = l + j (fwd) / tau = (63-l)+(511-j) (bwd). Strip-internal
// deps travel by register shuffles; strip boundaries via LDS rings; waves
// pipeline with a 2-superstep lag. R stored skew-major so each thread's
// global traffic is private and coalesced.

#define N_SEQ 512
#define GAMMA 0.01f
#define INVG  100.0f
#define BIG   1e10f
#define ALPHA 0.5f

#define NW   8                      // waves per block (strips)
#define H    64                     // rows per strip (= wave size)
#define TLOC (N_SEQ + H - 1)        // 575 local steps per strip
#define TPAD 576                    // padded slab row count
#define CC   64                     // steps per superstep
#define MLOC ((TLOC + CC - 1) / CC) // 9 supersteps of local work
#define LAG  2                      // superstep lag between adjacent waves
#define SST  (LAG * (NW - 1) + MLOC) // 23 supersteps per pass

#define SLABF ((size_t)NW * TPAD * H)   // floats per sample slab

__global__ __launch_bounds__(512) void dilate_fused(
    const float* __restrict__ outp, const float* __restrict__ targ,
    float* __restrict__ Rg, float* __restrict__ vals, float* __restrict__ svals,
    int kbase)
{
    const int tid = threadIdx.x;
    const int w   = tid >> 6;
    const int l   = tid & 63;
    const int i   = tid;                  // global row
    const int k   = kbase + blockIdx.x;

    __shared__ float o_sh[N_SEQ];
    __shared__ float t_sh[N_SEQ];
    __shared__ float Rb[NW][N_SEQ];       // fwd: R[64w+63][j] ; bwd: R[64w][j]
    __shared__ float Eb[NW][N_SEQ];       // bwd: E[64w][j]
    __shared__ float red[NW];

    o_sh[tid] = outp[(size_t)k * N_SEQ + tid];
    const float ti = targ[(size_t)k * N_SEQ + i];
    t_sh[tid] = ti;
    __syncthreads();

    float* __restrict__ slab = Rg + (size_t)blockIdx.x * SLABF + (size_t)w * TPAD * H;

    // ---------------- forward: R[i,j] = D + softmin(a,b,c) ----------------
    float r1 = BIG, r2 = BIG;             // own R at steps t-1, t-2
    for (int ss = 0; ss < SST; ++ss) {
        const int m = ss - LAG * w;
        if (m >= 0 && m < MLOC) {
            const int t0   = m * CC;
            const int tend = (t0 + CC < TLOC) ? t0 + CC : TLOC;
            for (int t = t0; t < tend; ++t) {
                const int j = t - l;
                const bool act = (j >= 0) && (j < N_SEQ);
                float a = __shfl_up(r1, 1);   // R[i-1, j]   (lane l-1, step t-1)
                float b = __shfl_up(r2, 1);   // R[i-1, j-1] (lane l-1, step t-2)
                float r0 = BIG;
                if (act) {
                    if (l == 0) {             // strip boundary: row 64w-1 from LDS
                        if (w > 0) {
                            a = Rb[w - 1][j];
                            b = (j >= 1) ? Rb[w - 1][j - 1] : BIG;
                        } else {
                            a = BIG;
                            b = (j == 0) ? 0.0f : BIG;   // virtual R[-1,-1]=0
                        }
                    }
                    const float c = r1;        // R[i, j-1]
                    const float mn = fminf(a, fminf(b, c));
                    const float s  = __expf((mn - a) * INVG)
                                   + __expf((mn - b) * INVG)
                                   + __expf((mn - c) * INVG);
                    const float sm = mn - GAMMA * __logf(s);
                    const float dv = ti - o_sh[j];
                    r0 = fmaf(dv, dv, sm);
                    r2 = r1; r1 = r0;
                    if (l == 63) Rb[w][j] = r0;            // boundary for wave w+1
                    if (i == N_SEQ - 1 && j == N_SEQ - 1) vals[k] = r0;
                }
                slab[t * H + l] = r0;          // skew-major, coalesced, private
            }
        }
        __syncthreads();
    }

    // ---------------- backward: E recursion + temporal accumulation --------
    const float tnext = (i + 1 < N_SEQ) ? t_sh[i + 1] : 0.0f;
    float e1 = 0.0f, e2 = 0.0f;           // own E at bwd steps tau-1, tau-2
    float prev1 = BIG, prev2 = BIG;       // own R rows t+1, t+2
    float acc = 0.0f;
    const int wr = (NW - 1) - w;          // bwd pipeline order (wave 7 first)
    for (int ss = 0; ss < SST; ++ss) {
        const int m = ss - LAG * wr;
        if (m >= 0 && m < MLOC) {
            const int t0   = m * CC;
            const int tend = (t0 + CC < TLOC) ? t0 + CC : TLOC;
            for (int tau = t0; tau < tend; ++tau) {
                const int t = (TLOC - 1) - tau;        // skew row, same all lanes
                const float rrow = slab[t * H + l];    // R[i, j] (own, coalesced)
                const int j = t - l;
                const bool act = (j >= 0) && (j < N_SEQ);
                float eA = __shfl_down(e1, 1);         // E[i+1, j]
                float eB = __shfl_down(e2, 1);         // E[i+1, j+1]
                float rA = __shfl_down(prev1, 1);      // R[i+1, j]
                float rB = __shfl_down(prev2, 1);      // R[i+1, j+1]
                float Ecur = 0.0f;
                if (act) {
                    const float rij = rrow;
                    const bool hasD = (i + 1 < N_SEQ);
                    const bool hasR = (j + 1 < N_SEQ);
                    if (l == 63 && hasD) {             // strip boundary from LDS
                        eA = Eb[w + 1][j];
                        rA = Rb[w + 1][j];
                        if (hasR) { eB = Eb[w + 1][j + 1]; rB = Rb[w + 1][j + 1]; }
                    }
                    float e = 0.0f;
                    const float oj = o_sh[j];
                    if (hasD) {                        // child (i+1, j)
                        const float dv = tnext - oj;
                        e += eA * __expf((rA - dv * dv - rij) * INVG);
                    }
                    if (hasR) {                        // child (i, j+1)
                        const float oj1 = o_sh[j + 1];
                        const float dv3 = ti - oj1;
                        e += e1 * __expf((prev1 - dv3 * dv3 - rij) * INVG);
                        if (hasD) {                    // child (i+1, j+1)
                            const float dv2 = tnext - oj1;
                            e += eB * __expf((rB - dv2 * dv2 - rij) * INVG);
                        }
                    }
                    if (i == N_SEQ - 1 && j == N_SEQ - 1) e = 1.0f;  // seed
                    Ecur = e;
                    const float diff = (float)(i - j);
                    acc = fmaf(Ecur * diff, diff, acc);
                    if (l == 0) { Eb[w][j] = Ecur; Rb[w][j] = rij; }
                }
                e2 = e1; e1 = Ecur;                    // unconditional rotates
                prev2 = prev1; prev1 = rrow;
            }
        }
        __syncthreads();
    }

    // block reduction of temporal accumulator
    for (int off = 32; off; off >>= 1) acc += __shfl_down(acc, off);
    if (l == 0) red[w] = acc;
    __syncthreads();
    if (tid == 0) {
        float s = 0.0f;
        for (int q = 0; q < NW; ++q) s += red[q];
        svals[k] = s;
    }
}

__global__ void finalize_kernel(const float* __restrict__ vals,
                                const float* __restrict__ svals,
                                float* __restrict__ out, int B) {
    int t = threadIdx.x;
    float v = 0.0f, s = 0.0f;
    for (int q = t; q < B; q += 64) { v += vals[q]; s += svals[q]; }
    for (int off = 32; off; off >>= 1) { v += __shfl_down(v, off); s += __shfl_down(s, off); }
    if (t == 0) {
        float loss_shape = v / (float)B;
        float loss_temporal = (s / (float)B) / ((float)N_SEQ * (float)N_SEQ);
        out[0] = ALPHA * loss_shape + (1.0f - ALPHA) * loss_temporal;
    }
}

extern "C" void kernel_launch(void* const* d_in, const int* in_sizes, int n_in,
                              void* d_out, int out_size, void* d_ws, size_t ws_size,
                              hipStream_t stream) {
    const float* outputs = (const float*)d_in[0];
    const float* targets = (const float*)d_in[1];
    const int B = in_sizes[0] / N_SEQ;    // 64

    // ws layout: [0,512B) vals, [512,1024B) svals, [1024, ...) R slabs
    float* vals  = (float*)d_ws;
    float* svals = vals + 128;
    float* Rws   = vals + 256;

    const size_t slab_bytes = SLABF * sizeof(float);
    size_t avail = (ws_size > 1024) ? (ws_size - 1024) / slab_bytes : 0;
    int G = (int)((avail < (size_t)B) ? avail : (size_t)B);
    if (G < 1) G = 1;

    for (int kb = 0; kb < B; kb += G) {
        int g = (B - kb < G) ? (B - kb) : G;
        dilate_fused<<<dim3(g), dim3(512), 0, stream>>>(outputs, targets, Rws, vals, svals, kb);
    }
    finalize_kernel<<<dim3(1), dim3(64), 0, stream>>>(vals, svals, (float*)d_out, B);
}

// Round 3
// 571.805 us; speedup vs baseline: 1.6651x; 1.6651x over previous
//
#include <hip/hip_runtime.h>
#include <hip/hip_bf16.h>

// DILATE loss: fused soft-DTW fwd+bwd, 4 waves/sample, 2 rows/lane, lag-1
// superstep pipeline (CC=64 diagonals), LDS column arrays for strip
// boundaries, 8-deep prefetch ring for the bwd R reload.
// Scaled domain: R'' = R * (100/ln2) so softmin/weights use raw exp2/log2.

#define NSEQ 512
#define K2   144.269504088896f      // (1/gamma)*log2(e) = 100/ln2
#define SC   0.006931471805599453f  // inverse scale = ln2/100
#define BIGV 1e10f
#define NEGV -1e30f
#define ALPHA 0.5f

#define WST   640                     // stored local diagonal steps per wave
#define SLAB2 ((size_t)4 * WST * 64)  // float2 elements per sample

__global__ __launch_bounds__(256) void dilate_fused(
    const float* __restrict__ outp, const float* __restrict__ targ,
    float2* __restrict__ slabAll, float* __restrict__ vals,
    float* __restrict__ svals, int kbase)
{
    const int tid = threadIdx.x;
    const int w = tid >> 6, l = tid & 63;
    const int i0 = 128 * w + 2 * l;          // lane owns rows i0, i0+1
    const int k = kbase + blockIdx.x;
    const bool lane0 = (l == 0), lane63 = (l == 63);

    __shared__ float o_pad[644];   // o[-1..642] at [j+1], pads = 0
    __shared__ float t_sh[516];
    __shared__ float Rbf[3][644];  // fwd boundary: row 128(w+1)-1 by column (col c at [c+1])
    __shared__ float dummyF[644];  // virtual row -1: [0]=0 (R[-1,-1]), else BIG
    __shared__ float Rbb[3][644];  // bwd boundary R: row 128(w+1) (col c at [c+1])
    __shared__ float Ebb[3][644];  // bwd boundary E
    __shared__ float dummyZ[644];  // zeros (row 512 virtual)
    __shared__ float red[4];

    for (int q = tid; q < 644; q += 256) {
        o_pad[q] = 0.f; dummyF[q] = BIGV; dummyZ[q] = 0.f;
    }
    for (int q = tid; q < 516; q += 256) t_sh[q] = 0.f;
    __syncthreads();
    if (tid == 0) {
        dummyF[0] = 0.f;                       // virtual R[-1,-1] = 0
        Rbf[0][0] = BIGV; Rbf[1][0] = BIGV; Rbf[2][0] = BIGV;
        Rbb[0][0] = NEGV; Rbb[1][0] = NEGV; Rbb[2][0] = NEGV;
        Ebb[0][0] = 0.f;  Ebb[1][0] = 0.f;  Ebb[2][0] = 0.f;
    }
    for (int q = tid; q < NSEQ; q += 256) {
        o_pad[1 + q] = outp[(size_t)k * NSEQ + q];
        t_sh[q]      = targ[(size_t)k * NSEQ + q];
    }
    __syncthreads();

    const float t0 = t_sh[i0], t1 = t_sh[i0 + 1], t2 = t_sh[i0 + 2];

    const float* RbfR = (w == 0) ? dummyF : Rbf[w - 1];
    float*       RbfW = Rbf[w < 3 ? w : 2];          // guarded by (w<3)
    const float* RbbR = (w == 3) ? dummyZ : Rbb[w];
    const float* EbbR = (w == 3) ? dummyZ : Ebb[w];
    float*       RbbW = Rbb[(w > 0 ? w : 1) - 1];    // guarded by (w>0)
    float*       EbbW = Ebb[(w > 0 ? w : 1) - 1];

    float2* __restrict__ sp = slabAll + (size_t)blockIdx.x * SLAB2
                              + (size_t)(w * WST) * 64 + l;

    // ---------------- forward ----------------
    float rp1_0 = BIGV, rp1_1 = BIGV, rp2_0 = BIGV, rp2_1 = BIGV;
    float rfinal = BIGV;

    for (int ss = 0; ss < 19; ++ss) {
        const int mw = ss - 3 * w;               // wave-local window
        if (0 <= mw && mw < 10) {
            const int tb  = (mw + 2 * w) * 64;   // global diag base
            const int tl0 = mw * 64;             // local stored index base
            int j0 = tb - i0;
            #pragma unroll 8
            for (int u = 0; u < 64; ++u, ++j0) {
                const int ob = (j0 > 0) ? j0 : 0;
                const float oj  = o_pad[ob + 1];     // o[j0]
                const float ojm = o_pad[ob];         // o[j0-1]
                const float bdA = RbfR[ob + 1];      // R[i0-1, j0]
                const float bdB = RbfR[ob];          // R[i0-1, j0-1]
                const float sA = __shfl_up(rp1_1, 1);
                const float sB = __shfl_up(rp2_1, 1);
                const float a0 = lane0 ? bdA : sA;
                const float b0 = lane0 ? bdB : sB;
                const float c0 = rp1_0;
                // cell r=0: (i0, j0)
                float mn0 = fminf(fminf(a0, b0), c0);
                float s0 = __builtin_exp2f(mn0 - a0) + __builtin_exp2f(mn0 - b0)
                         + __builtin_exp2f(mn0 - c0);
                float sm0 = mn0 - __builtin_log2f(s0);
                float dv0 = t0 - oj;
                float r0v = fmaf(dv0 * dv0, K2, sm0);
                // cell r=1: (i0+1, j0-1) — uses only pre-rotation registers
                float mn1 = fminf(fminf(rp1_0, rp2_0), rp1_1);
                float s1 = __builtin_exp2f(mn1 - rp1_0) + __builtin_exp2f(mn1 - rp2_0)
                         + __builtin_exp2f(mn1 - rp1_1);
                float sm1 = mn1 - __builtin_log2f(s1);
                float dv1 = t1 - ojm;
                float r1v = fmaf(dv1 * dv1, K2, sm1);
                const bool act0 = ((unsigned)j0 < 512u);
                const bool act1 = ((unsigned)(j0 - 1) < 512u);
                const float r0n = act0 ? r0v : BIGV;
                const float r1n = act1 ? r1v : BIGV;
                rp2_0 = rp1_0; rp1_0 = r0n;
                rp2_1 = rp1_1; rp1_1 = r1n;
                float2 st; st.x = act0 ? r0v : NEGV; st.y = act1 ? r1v : NEGV;
                sp[(size_t)(tl0 + u) * 64] = st;
                if (lane63 && w < 3 && act1) RbfW[j0] = r1n;  // col j0-1 at [j0]
                if (u == 62 && mw == 9) rfinal = r1v;         // (511,511) on wave 3
            }
        }
        asm volatile("s_waitcnt lgkmcnt(0)\n\ts_barrier" ::: "memory");
    }

    // phase transition: own-thread store->load ordering for the slab
    asm volatile("s_waitcnt vmcnt(0)" ::: "memory");
    if (w == 3 && lane63) vals[k] = rfinal * SC;

    // ---------------- backward ----------------
    float ep1_0 = 0.f, ep1_1 = 0.f, ep2_0 = 0.f, ep2_1 = 0.f;
    rp1_0 = NEGV; rp1_1 = NEGV; rp2_0 = NEGV; rp2_1 = NEGV;
    float acc = 0.f;

    const int j0s = 639 - 2 * l;                 // j0 at first bwd step
    float ocar = o_pad[j0s + 2];                 // o[j0s+1]
    const float otmp = o_pad[j0s + 1];           // o[j0s]
    float dB0 = (t1 - ocar) * (t1 - ocar);       // carry: (t1 - o[j0+1])^2
    float dB1 = (t2 - otmp) * (t2 - otmp);       // carry: (t2 - o[j0])^2

    float2 ring[8];
    #pragma unroll
    for (int p = 0; p < 8; ++p) ring[(639 - p) & 7] = sp[(size_t)(639 - p) * 64];

    for (int ssb = 0; ssb < 19; ++ssb) {
        const int mw = 18 - 3 * w - ssb;
        if (0 <= mw && mw < 10) {
            const int tb  = (mw + 2 * w) * 64;
            const int tl0 = mw * 64;
            float dif0 = (float)(2 * i0 - (tb + 63));   // i0 - j0 at u=0
            int j0 = tb + 63 - i0;
            for (int ub = 0; ub < 8; ++ub) {
                #pragma unroll
                for (int uq = 0; uq < 8; ++uq) {
                    const int u = ub * 8 + uq;
                    const int tl = tl0 + 63 - u;
                    const int slot = 7 - uq;             // == tl & 7
                    const float2 rc = ring[slot];        // R(t) rows i0, i0+1
                    {   // prefetch t-8
                        int tln = tl - 8; if (tln < 0) tln = 0;
                        ring[slot] = sp[(size_t)tln * 64];
                    }
                    const int ob = (j0 > 0) ? j0 : 0;
                    const float ojm = o_pad[ob];         // o[j0-1]
                    const float oj  = o_pad[ob + 1];     // o[j0]
                    const float bR0 = RbbR[ob];          // R[128(w+1), j0-1]
                    const float bR1 = RbbR[ob + 1];      // R[128(w+1), j0]
                    const float bE0 = EbbR[ob];
                    const float bE1 = EbbR[ob + 1];
                    const float shR1 = __shfl_down(rp1_0, 1);
                    const float shR2 = __shfl_down(rp2_0, 1);
                    const float shE1 = __shfl_down(ep1_0, 1);
                    const float shE2 = __shfl_down(ep2_0, 1);
                    const float rA1 = lane63 ? bR0 : shR1;  // R[i0+2, j0-1] (t+1)
                    const float rB1 = lane63 ? bR1 : shR2;  // R[i0+2, j0]   (t+2)
                    const float eA1 = lane63 ? bE0 : shE1;
                    const float eB1 = lane63 ? bE1 : shE2;
                    const float rij0 = rc.x, rij1 = rc.y;
                    const float dvA0 = t1 - oj;  const float dA0 = dvA0 * dvA0;
                    const float dvC0 = t0 - ocar; const float dC0 = dvC0 * dvC0;
                    const float dvA1 = t2 - ojm; const float dA1 = dvA1 * dvA1;
                    // cell r=0 (i0, j0): children (i0+1,j0),(i0,j0+1),(i0+1,j0+1)
                    float e0 = ep1_1 * __builtin_exp2f(fmaf(dA0, -K2, rp1_1 - rij0));
                    e0 = fmaf(ep1_0, __builtin_exp2f(fmaf(dC0, -K2, rp1_0 - rij0)), e0);
                    e0 = fmaf(ep2_1, __builtin_exp2f(fmaf(dB0, -K2, rp2_1 - rij0)), e0);
                    // cell r=1 (i0+1, j0-1): children (i0+2,j0-1),(i0+1,j0),(i0+2,j0)
                    float e1 = eA1 * __builtin_exp2f(fmaf(dA1, -K2, rA1 - rij1));
                    e1 = fmaf(ep1_1, __builtin_exp2f(fmaf(dA0, -K2, rp1_1 - rij1)), e1);
                    e1 = fmaf(eB1, __builtin_exp2f(fmaf(dB1, -K2, rB1 - rij1)), e1);
                    const bool act0 = ((unsigned)j0 < 512u);
                    const bool act1 = ((unsigned)(j0 - 1) < 512u);
                    float E0 = act0 ? e0 : 0.f;
                    float E1 = act1 ? e1 : 0.f;
                    if (u == 1 && mw == 9 && w == 3 && lane63) E1 = 1.0f; // seed (511,511)
                    const float d1f = dif0 + 2.0f;
                    acc = fmaf(E0 * dif0, dif0, acc);
                    acc = fmaf(E1 * d1f, d1f, acc);
                    if (lane0 && w > 0) { RbbW[j0 + 1] = rij0; EbbW[j0 + 1] = E0; }
                    rp2_0 = rp1_0; rp1_0 = rij0;
                    rp2_1 = rp1_1; rp1_1 = rij1;
                    ep2_0 = ep1_0; ep1_0 = E0;
                    ep2_1 = ep1_1; ep1_1 = E1;
                    dB0 = dA0; dB1 = dA1;
                    ocar = oj;
                    dif0 += 1.0f;
                    --j0;
                }
            }
        }
        asm volatile("s_waitcnt lgkmcnt(0)\n\ts_barrier" ::: "memory");
    }

    for (int off = 32; off; off >>= 1) acc += __shfl_down(acc, off);
    if (lane0) red[w] = acc;
    __syncthreads();
    if (tid == 0) svals[k] = red[0] + red[1] + red[2] + red[3];
}

__global__ void finalize_kernel(const float* __restrict__ vals,
                                const float* __restrict__ svals,
                                float* __restrict__ out, int B) {
    int t = threadIdx.x;
    float v = 0.0f, s = 0.0f;
    for (int q = t; q < B; q += 64) { v += vals[q]; s += svals[q]; }
    for (int off = 32; off; off >>= 1) { v += __shfl_down(v, off); s += __shfl_down(s, off); }
    if (t == 0) {
        float loss_shape = v / (float)B;
        float loss_temporal = (s / (float)B) / ((float)NSEQ * (float)NSEQ);
        out[0] = ALPHA * loss_shape + (1.0f - ALPHA) * loss_temporal;
    }
}

extern "C" void kernel_launch(void* const* d_in, const int* in_sizes, int n_in,
                              void* d_out, int out_size, void* d_ws, size_t ws_size,
                              hipStream_t stream) {
    const float* outputs = (const float*)d_in[0];
    const float* targets = (const float*)d_in[1];
    const int B = in_sizes[0] / NSEQ;    // 64

    float* vals  = (float*)d_ws;
    float* svals = vals + 128;
    float2* slab = (float2*)((char*)d_ws + 1024);

    const size_t slab_bytes = SLAB2 * sizeof(float2);   // ~1.31 MB/sample
    size_t avail = (ws_size > 1024) ? (ws_size - 1024) / slab_bytes : 0;
    int G = (int)((avail < (size_t)B) ? avail : (size_t)B);
    if (G < 1) G = 1;

    for (int kb = 0; kb < B; kb += G) {
        int g = (B - kb < G) ? (B - kb) : G;
        dilate_fused<<<dim3(g), dim3(256), 0, stream>>>(outputs, targets, slab, vals, svals, kb);
    }
    finalize_kernel<<<dim3(1), dim3(64), 0, stream>>>(vals, svals, (float*)d_out, B);
}